// Round 7
// baseline (237.350 us; speedup 1.0000x reference)
//
#include <hip/hip_runtime.h>

// LSS voxel pooling: B=2,N=6,D=48,FH=16,FW=44,C=80 -> out [2,80,1,256,256]
//
// R12: cross-round accounting shows gather_tiled ~50us (6x floor) -- the
// per-voxel LIFO linked list was the bottleneck: hot near-camera voxels
// hold ~40+ entries (44 w-cols collapse to ~7 gy bins at d~2m, x 6 equal-R
// cameras), so CAP=16 forced per-item serial pointer-chases (~300cy/hop,
// redundant x20 threads). Fix: slot arrays -- geom registers entries via
// vcnt[vox]++ -> slots[vox*64+idx]; gather reads IDs with plain loads (no
// chases, no LDS chain staging). Overflow >64/voxel -> global pair list
// (correctness net, expected empty). Also: run-encoded meta (h0,len) so
// reduce reads only live rows (66->35MB), float4 out writes.
// Predicted: gather 10-14us, reduce 8-10us, total ~185-200.
//
// Numerics: f64 geometry seeded with bit-exact f32 frustum values +
// f32-valued bounds constants; trunc-toward-zero. Per-entry f32 h-sum in
// reference (h-ascending) order; f32 across entries (validated R6-R11).

#define NCH       80
#define GRID_HW   65536    // 256*256
#define OUT_PER_B 5242880  // 80*65536
#define HSTRIDE   3520     // 44*80 floats between h rows
#define PTS_PER_BN 33792   // 48*16*44
#define NCOLS     25344    // 576 slices * 44 cols
#define SLOT_STRIDE 64

// workspace layout (bytes)
#define N_ENT_MAX 405504           // 25344 cols x 16 groups worst case
#define P_BYTES    129761280u      // N_ENT_MAX * 80 * 4
#define SLOTS_OFF  129761280u      // 131072 * 64 * 4 = 33554432
#define VCNT_OFF   163315712u      // 131072 * 4     = 524288
#define CTR_OFF    163840000u      // 256  ([0]=entry ctr, [1]=ovf ctr)
#define META_OFF   163840256u      // N_ENT_MAX * 4  = 1622016
#define OVF_OFF    165462272u      // 65536 * 8      = 524288
#define WS_NEED    165986560u

__device__ inline void inv3(const double a[9], double inv[9]) {
    double c00 =  a[4]*a[8] - a[5]*a[7];
    double c01 = -(a[3]*a[8] - a[5]*a[6]);
    double c02 =  a[3]*a[7] - a[4]*a[6];
    double det = a[0]*c00 + a[1]*c01 + a[2]*c02;
    double id  = 1.0/det;
    inv[0] = c00*id;
    inv[1] = (a[2]*a[7]-a[1]*a[8])*id;
    inv[2] = (a[1]*a[5]-a[2]*a[4])*id;
    inv[3] = c01*id;
    inv[4] = (a[0]*a[8]-a[2]*a[6])*id;
    inv[5] = (a[2]*a[3]-a[0]*a[5])*id;
    inv[6] = c02*id;
    inv[7] = (a[1]*a[6]-a[0]*a[7])*id;
    inv[8] = (a[0]*a[4]-a[1]*a[3])*id;
}

// o[0..8]=inv(post_rots), [9..17]=rots@inv(intrins), [18..20]=post_trans, [21..23]=trans
__device__ inline void prep_bn(const float* __restrict__ rots,
                               const float* __restrict__ trans,
                               const float* __restrict__ intrins,
                               const float* __restrict__ post_rots,
                               const float* __restrict__ post_trans,
                               int bn, double* o) {
    double pr[9], kk[9], rt[9], ipr[9], ik[9];
    #pragma unroll
    for (int i = 0; i < 9; i++) {
        pr[i] = (double)post_rots[bn*9 + i];
        kk[i] = (double)intrins[bn*9 + i];
        rt[i] = (double)rots[bn*9 + i];
    }
    inv3(pr, ipr);
    inv3(kk, ik);
    #pragma unroll
    for (int i = 0; i < 9; i++) o[i] = ipr[i];
    #pragma unroll
    for (int r = 0; r < 3; r++)
        #pragma unroll
        for (int c = 0; c < 3; c++)
            o[9 + r*3 + c] = rt[r*3+0]*ik[0*3+c] + rt[r*3+1]*ik[1*3+c] + rt[r*3+2]*ik[2*3+c];
    #pragma unroll
    for (int i = 0; i < 3; i++) o[18 + i] = (double)post_trans[bn*3 + i];
    #pragma unroll
    for (int i = 0; i < 3; i++) o[21 + i] = (double)trans[bn*3 + i];
}

__global__ void prep_kernel(const float* __restrict__ rots,
                            const float* __restrict__ trans,
                            const float* __restrict__ intrins,
                            const float* __restrict__ post_rots,
                            const float* __restrict__ post_trans,
                            double* __restrict__ tw) {
    int bn = threadIdx.x;
    if (bn >= 12) return;
    prep_bn(rots, trans, intrins, post_rots, post_trans, bn, tw + bn*24);
}

__global__ __launch_bounds__(256) void zero_kernel(float4* __restrict__ p, int n4) {
    int i = blockIdx.x * 256 + threadIdx.x;
    int stride = gridDim.x * 256;
    for (; i < n4; i += stride) p[i] = make_float4(0.f, 0.f, 0.f, 0.f);
}

// zero vcnt (131072 ints as 32768 int4; 128 blk x 256 = exactly one each) + ctrs
__global__ __launch_bounds__(256) void init_cnt(int4* __restrict__ vcnt4, int* __restrict__ ctr) {
    int i = blockIdx.x * 256 + threadIdx.x;
    vcnt4[i] = make_int4(0, 0, 0, 0);
    if (i == 0) { ctr[0] = 0; ctr[1] = 0; }
}

// K1: one thread per column (99 blk x 256 = 25344). Transforms in LDS,
// run-length grouping over static vox[16], wave-aggregated entry alloc,
// slot registration (no linked list).
__global__ __launch_bounds__(256) void geom_cols(const float* __restrict__ rots,
                                                 const float* __restrict__ trans,
                                                 const float* __restrict__ intrins,
                                                 const float* __restrict__ post_rots,
                                                 const float* __restrict__ post_trans,
                                                 int* __restrict__ slots,
                                                 int* __restrict__ vcnt,
                                                 int* __restrict__ ctr,
                                                 unsigned* __restrict__ ent_meta,
                                                 int2* __restrict__ ovf) {
    __shared__ double s_t[12 * 24];

    const int tid  = threadIdx.x;
    const int col  = blockIdx.x * 256 + tid;
    const int lane = tid & 63;

    if (tid < 12)
        prep_bn(rots, trans, intrins, post_rots, post_trans, tid, s_t + tid * 24);
    __syncthreads();

    const int slice = col / 44;                   // bn*48 + d
    const int w     = col - slice * 44;
    const int bn    = slice / 48;
    const int d     = slice - bn * 48;
    const int b     = bn / 6;
    const double* t = s_t + bn * 24;

    // per-h voxel ids (statically indexed -> registers)
    int vox[16];
    {
        const float dsv = __fadd_rn(2.0f, __fmul_rn((float)(56.0 / 48.0), (float)d));
        const float xsv = (w == 43) ? 703.0f : (float)((double)w * (703.0 / 43.0));
        const double px = (double)xsv - t[18];
        #pragma unroll
        for (int h = 0; h < 16; h++) {
            float ysv = (float)(h * 17);
            double py = (double)ysv - t[19];
            double pz = (double)dsv - t[20];
            double q0 = t[0]*px + t[1]*py + t[2]*pz;
            double q1 = t[3]*px + t[4]*py + t[5]*pz;
            double q2 = t[6]*px + t[7]*py + t[8]*pz;
            q0 *= q2;
            q1 *= q2;
            double e0 = t[9]*q0  + t[10]*q1 + t[11]*q2 + t[21];
            double e1 = t[12]*q0 + t[13]*q1 + t[14]*q2 + t[22];
            double e2 = t[15]*q0 + t[16]*q1 + t[17]*q2 + t[23];
            const double lxy = (double)(-51.2f);
            const double dxy = (double)(0.4f);
            int gx = (int)((e0 - lxy) / dxy);
            int gy = (int)((e1 - lxy) / dxy);
            int gz = (int)((e2 - (double)(-10.0f)) / (double)(20.0f));
            vox[h] = (gx >= 0 && gx < 256 && gy >= 0 && gy < 256 && gz == 0)
                   ? ((b << 16) | (gy << 8) | gx) : -1;
        }
    }

    // count run-length groups (break at -1 or id change)
    int cnt = 0;
    #pragma unroll
    for (int h = 0; h < 16; h++) {
        int prev = (h == 0) ? -1 : vox[h - 1];
        if (vox[h] >= 0 && vox[h] != prev) cnt++;
    }

    // wave-aggregated allocation (1 atomic per wave)
    int pre = cnt;
    #pragma unroll
    for (int off = 1; off < 64; off <<= 1) {
        int n = __shfl_up(pre, off);
        if (lane >= off) pre += n;
    }
    int wtot  = __shfl(pre, 63);
    int wbase = 0;
    if (wtot > 0) {
        if (lane == 63) wbase = atomicAdd(&ctr[0], wtot);
        wbase = __shfl(wbase, 63);
    }
    int e = wbase + pre - cnt;    // my first entry index

    // emit runs: meta = slice<<22 | w<<16 | h0<<5 | len; register in slots
    int cur = -1; int h0 = 0, len = 0;
    #pragma unroll
    for (int h = 0; h < 16; h++) {
        if (vox[h] < 0) {
            if (cur >= 0) {
                ent_meta[e] = ((unsigned)slice << 22) | ((unsigned)w << 16)
                            | ((unsigned)h0 << 5) | (unsigned)len;
                int idx = atomicAdd(&vcnt[cur], 1);
                if (idx < SLOT_STRIDE) slots[(size_t)cur * SLOT_STRIDE + idx] = e;
                else { int o = atomicAdd(&ctr[1], 1); if (o < 65536) ovf[o] = make_int2(cur, e); }
                e++; cur = -1; len = 0;
            }
        } else if (vox[h] != cur) {
            if (cur >= 0) {
                ent_meta[e] = ((unsigned)slice << 22) | ((unsigned)w << 16)
                            | ((unsigned)h0 << 5) | (unsigned)len;
                int idx = atomicAdd(&vcnt[cur], 1);
                if (idx < SLOT_STRIDE) slots[(size_t)cur * SLOT_STRIDE + idx] = e;
                else { int o = atomicAdd(&ctr[1], 1); if (o < 65536) ovf[o] = make_int2(cur, e); }
                e++;
            }
            cur = vox[h]; h0 = h; len = 1;
        } else {
            len++;
        }
    }
    if (cur >= 0) {
        ent_meta[e] = ((unsigned)slice << 22) | ((unsigned)w << 16)
                    | ((unsigned)h0 << 5) | (unsigned)len;
        int idx = atomicAdd(&vcnt[cur], 1);
        if (idx < SLOT_STRIDE) slots[(size_t)cur * SLOT_STRIDE + idx] = e;
        else { int o = atomicAdd(&ctr[1], 1); if (o < 65536) ovf[o] = make_int2(cur, e); }
    }
}

// K2: balanced streaming reduce x -> P. One item = (entry, c4); reads ONLY
// the live h-run [h0, h0+len) (4-unrolled so loads issue in bursts).
__global__ __launch_bounds__(256) void reduce_kernel(const float* __restrict__ x,
                                                     const unsigned* __restrict__ ent_meta,
                                                     const int* __restrict__ ctr,
                                                     float* __restrict__ P) {
    const int NE = ctr[0];
    const int total = NE * 20;
    int i = blockIdx.x * 256 + threadIdx.x;
    const int stride = gridDim.x * 256;
    for (; i < total; i += stride) {
        int e  = i / 20;
        int c4 = i - e * 20;
        unsigned m = ent_meta[e];
        int slice = (int)(m >> 22);
        int w     = (int)((m >> 16) & 63u);
        int h0    = (int)((m >> 5) & 15u);
        int len   = (int)(m & 31u);
        const float* xb = x + (size_t)(slice * 704 + w) * NCH
                            + (size_t)h0 * HSTRIDE + c4 * 4;
        float ax = 0.f, ay = 0.f, az = 0.f, aw = 0.f;
        int hh = 0;
        for (; hh + 4 <= len; hh += 4) {     // burst of 4 independent loads
            float4 v0 = *(const float4*)(xb + (size_t)(hh + 0) * HSTRIDE);
            float4 v1 = *(const float4*)(xb + (size_t)(hh + 1) * HSTRIDE);
            float4 v2 = *(const float4*)(xb + (size_t)(hh + 2) * HSTRIDE);
            float4 v3 = *(const float4*)(xb + (size_t)(hh + 3) * HSTRIDE);
            ax += v0.x; ay += v0.y; az += v0.z; aw += v0.w;
            ax += v1.x; ay += v1.y; az += v1.z; aw += v1.w;
            ax += v2.x; ay += v2.y; az += v2.z; aw += v2.w;
            ax += v3.x; ay += v3.y; az += v3.z; aw += v3.w;
        }
        for (; hh < len; hh++) {
            float4 v = *(const float4*)(xb + (size_t)hh * HSTRIDE);
            ax += v.x; ay += v.y; az += v.z; aw += v.w;
        }
        float4 r; r.x = ax; r.y = ay; r.z = az; r.w = aw;
        *(float4*)(P + (size_t)e * NCH + c4 * 4) = r;   // 320B contiguous
    }
}

// K3: per 64-voxel tile: read slot IDs directly (no pointer chase, no chain
// staging), one float4 P-load per (entry,c4), LDS transpose, float4 out.
__global__ __launch_bounds__(256, 6) void gather_slots(const float* __restrict__ P,
                                                       const int* __restrict__ slots,
                                                       const int* __restrict__ vcnt,
                                                       const int* __restrict__ ctr,
                                                       const int2* __restrict__ ovf,
                                                       float* __restrict__ out) {
    __shared__ float tile[64 * 81];
    __shared__ int   s_cnt[64];
    __shared__ int   s_novf;

    const int tid = threadIdx.x;
    const int b   = blockIdx.x >> 10;
    const int v0  = (blockIdx.x & 1023) * 64;

    if (tid < 64) s_cnt[tid] = vcnt[(b << 16) + v0 + tid];
    if (tid == 0) s_novf = ctr[1];
    __syncthreads();

    // 64 vox * 20 c4-items = 1280 items, 5 passes
    #pragma unroll
    for (int i = 0; i < 5; i++) {
        int j  = i * 256 + tid;
        int v  = j / 20;
        int c4 = j - v * 20;
        const int vox = (b << 16) + v0 + v;
        const int cnt = s_cnt[v];
        const int cl  = (cnt < SLOT_STRIDE) ? cnt : SLOT_STRIDE;
        const int* sl = slots + (size_t)vox * SLOT_STRIDE;
        float ax = 0.f, ay = 0.f, az = 0.f, aw = 0.f;
        for (int k = 0; k < cl; k++) {
            int e = sl[k];                     // broadcast across 20 c4 lanes
            const float4 p = *(const float4*)(P + (size_t)e * NCH + c4 * 4);
            ax += p.x; ay += p.y; az += p.z; aw += p.w;
        }
        if (cnt > SLOT_STRIDE) {               // correctness net (expected never)
            int no = s_novf; if (no > 65536) no = 65536;
            for (int j2 = 0; j2 < no; j2++) {
                int2 pr = ovf[j2];
                if (pr.x == vox) {
                    const float4 p = *(const float4*)(P + (size_t)pr.y * NCH + c4 * 4);
                    ax += p.x; ay += p.y; az += p.z; aw += p.w;
                }
            }
        }
        tile[v * 81 + c4 * 4 + 0] = ax;
        tile[v * 81 + c4 * 4 + 1] = ay;
        tile[v * 81 + c4 * 4 + 2] = az;
        tile[v * 81 + c4 * 4 + 3] = aw;
    }
    __syncthreads();

    // float4 out writes: 1280 float4 / 256 threads = 5 iters
    #pragma unroll
    for (int i = 0; i < 5; i++) {
        int f   = i * 256 + tid;
        int c   = f >> 4;                 // 0..79
        int lv4 = f & 15;                 // 0..15 (16 float4 per c-row)
        float4 r;
        r.x = tile[(lv4 * 4 + 0) * 81 + c];
        r.y = tile[(lv4 * 4 + 1) * 81 + c];
        r.z = tile[(lv4 * 4 + 2) * 81 + c];
        r.w = tile[(lv4 * 4 + 3) * 81 + c];
        *(float4*)(out + (size_t)b * OUT_PER_B + (size_t)c * GRID_HW + v0 + lv4 * 4) = r;
    }
}

// ---- fallback path (ws too small): R3 structure ----
__device__ inline void geom_points(const double* __restrict__ t,
                                   int b, int d, int tid, int* s_base) {
    const float dsv = __fadd_rn(2.0f, __fmul_rn((float)(56.0 / 48.0), (float)d));
    for (int idx = tid; idx < 704; idx += 256) {
        const int h = idx / 44;
        const int w = idx - h * 44;
        float xsv = (w == 43) ? 703.0f : (float)((double)w * (703.0 / 43.0));
        float ysv = (float)(h * 17);
        double px = (double)xsv - t[18];
        double py = (double)ysv - t[19];
        double pz = (double)dsv - t[20];
        double q0 = t[0]*px + t[1]*py + t[2]*pz;
        double q1 = t[3]*px + t[4]*py + t[5]*pz;
        double q2 = t[6]*px + t[7]*py + t[8]*pz;
        q0 *= q2;
        q1 *= q2;
        double e0 = t[9]*q0  + t[10]*q1 + t[11]*q2 + t[21];
        double e1 = t[12]*q0 + t[13]*q1 + t[14]*q2 + t[22];
        double e2 = t[15]*q0 + t[16]*q1 + t[17]*q2 + t[23];
        const double lxy = (double)(-51.2f);
        const double dxy = (double)(0.4f);
        int gx = (int)((e0 - lxy) / dxy);
        int gy = (int)((e1 - lxy) / dxy);
        int gz = (int)((e2 - (double)(-10.0f)) / (double)(20.0f));
        int base = -1;
        if (gx >= 0 && gx < 256 && gy >= 0 && gy < 256 && gz == 0)
            base = (b << 16) | (gy << 8) | gx;
        s_base[idx] = base;
    }
}

__global__ __launch_bounds__(256) void scatter_direct_kernel(const float* __restrict__ x,
                                                             const double* __restrict__ ws,
                                                             float* __restrict__ out) {
    __shared__ int      s_base[704];
    __shared__ int      s_colbase[44];
    __shared__ unsigned s_mask[44];
    __shared__ unsigned s_fb[44];

    const int tid = threadIdx.x;
    const int bn  = blockIdx.x / 48;
    const int d   = blockIdx.x - bn * 48;
    const int b   = bn / 6;
    geom_points(ws + bn * 24, b, d, tid, s_base);
    __syncthreads();

    if (tid < 44) {
        int cb = -1; unsigned mm = 0, fb = 0;
        #pragma unroll
        for (int h = 0; h < 16; h++) {
            int pb = s_base[h * 44 + tid];
            if (pb >= 0) {
                if (cb < 0) cb = pb;
                if (pb == cb) mm |= (1u << h);
                else          fb |= (1u << h);
            }
        }
        s_colbase[tid] = cb;
        s_mask[tid]    = mm;
        s_fb[tid]      = fb;
    }
    __syncthreads();

    const float* xb0 = x + ((size_t)bn * PTS_PER_BN + (size_t)d * 704) * NCH;
    #pragma unroll
    for (int pass = 0; pass < 4; pass++) {
        int item = pass * 256 + tid;
        if (item >= 880) break;
        int w  = item / 20;
        int c4 = item - w * 20;
        unsigned mm = s_mask[w];
        unsigned fb = s_fb[w];
        if (!(mm | fb)) continue;
        const float* xb = xb0 + (size_t)w * NCH + c4 * 4;
        float ax = 0.f, ay = 0.f, az = 0.f, aw = 0.f;
        #pragma unroll
        for (int h = 0; h < 16; h++) {
            if ((mm >> h) & 1u) {
                float4 v = *(const float4*)(xb + h * HSTRIDE);
                ax += v.x; ay += v.y; az += v.z; aw += v.w;
            } else if ((fb >> h) & 1u) {
                float4 v = *(const float4*)(xb + h * HSTRIDE);
                int vb = s_base[h * 44 + w];
                float* o = out + (size_t)(vb >> 16) * OUT_PER_B + (vb & 65535);
                atomicAdd(o + (size_t)(c4*4 + 0) * GRID_HW, v.x);
                atomicAdd(o + (size_t)(c4*4 + 1) * GRID_HW, v.y);
                atomicAdd(o + (size_t)(c4*4 + 2) * GRID_HW, v.z);
                atomicAdd(o + (size_t)(c4*4 + 3) * GRID_HW, v.w);
            }
        }
        if (mm) {
            int vb = s_colbase[w];
            float* o = out + (size_t)(vb >> 16) * OUT_PER_B + (vb & 65535);
            atomicAdd(o + (size_t)(c4*4 + 0) * GRID_HW, ax);
            atomicAdd(o + (size_t)(c4*4 + 1) * GRID_HW, ay);
            atomicAdd(o + (size_t)(c4*4 + 2) * GRID_HW, az);
            atomicAdd(o + (size_t)(c4*4 + 3) * GRID_HW, aw);
        }
    }
}

extern "C" void kernel_launch(void* const* d_in, const int* in_sizes, int n_in,
                              void* d_out, int out_size, void* d_ws, size_t ws_size,
                              hipStream_t stream) {
    const float* x          = (const float*)d_in[0];
    const float* rots       = (const float*)d_in[1];
    const float* trans      = (const float*)d_in[2];
    const float* intrins    = (const float*)d_in[3];
    const float* post_rots  = (const float*)d_in[4];
    const float* post_trans = (const float*)d_in[5];
    float* out = (float*)d_out;

    if (ws_size >= (size_t)WS_NEED) {
        float*    P     = (float*)d_ws;
        int*      slots = (int*)((char*)d_ws + SLOTS_OFF);
        int*      vcnt  = (int*)((char*)d_ws + VCNT_OFF);
        int*      ctr   = (int*)((char*)d_ws + CTR_OFF);
        unsigned* meta  = (unsigned*)((char*)d_ws + META_OFF);
        int2*     ovf   = (int2*)((char*)d_ws + OVF_OFF);
        init_cnt<<<128, 256, 0, stream>>>((int4*)vcnt, ctr);
        geom_cols<<<99, 256, 0, stream>>>(rots, trans, intrins,
                                          post_rots, post_trans,
                                          slots, vcnt, ctr, meta, ovf);
        reduce_kernel<<<1024, 256, 0, stream>>>(x, meta, ctr, P);
        gather_slots<<<2048, 256, 0, stream>>>(P, slots, vcnt, ctr, ovf, out);
    } else if (ws_size >= 12 * 24 * sizeof(double)) {
        double* tw = (double*)d_ws;
        zero_kernel<<<2560, 256, 0, stream>>>((float4*)out, out_size / 16);
        prep_kernel<<<1, 64, 0, stream>>>(rots, trans, intrins, post_rots, post_trans, tw);
        scatter_direct_kernel<<<576, 256, 0, stream>>>(x, tw, out);
    }
}

// Round 8
// 236.865 us; speedup vs baseline: 1.0020x; 1.0020x over previous
//
#include <hip/hip_runtime.h>

// LSS voxel pooling: B=2,N=6,D=48,FH=16,FW=44,C=80 -> out [2,80,1,256,256]
//
// R13: R12 (+12.5us vs R11) bundled two edits; suspect is the run-encoded
// reduce: runtime-bounded h-loop dropped MLP 16->4 and added lane
// divergence (len varies in-wave) on a LATENCY-bound kernel -- saved
// FETCH bytes, paid latency. Revert reduce to the proven mask-fmaf
// unconditional-16-load form (meta = slice|w|mask16). KEEP R12's
// slot-array gather (no pointer chasing). Single-variable experiment:
//   ~222 => reduce was the regression (slots ok); ~237 => slots bad.
//
// Numerics: f64 geometry seeded with bit-exact f32 frustum values +
// f32-valued bounds constants; trunc-toward-zero. Per-entry f32 h-sum in
// reference (h-ascending) order; f32 across entries (validated R6-R12).

#define NCH       80
#define GRID_HW   65536    // 256*256
#define OUT_PER_B 5242880  // 80*65536
#define HSTRIDE   3520     // 44*80 floats between h rows
#define PTS_PER_BN 33792   // 48*16*44
#define NCOLS     25344    // 576 slices * 44 cols
#define SLOT_STRIDE 64

// workspace layout (bytes)
#define N_ENT_MAX 405504           // 25344 cols x 16 groups worst case
#define P_BYTES    129761280u      // N_ENT_MAX * 80 * 4
#define SLOTS_OFF  129761280u      // 131072 * 64 * 4 = 33554432
#define VCNT_OFF   163315712u      // 131072 * 4     = 524288
#define CTR_OFF    163840000u      // 256  ([0]=entry ctr, [1]=ovf ctr)
#define META_OFF   163840256u      // N_ENT_MAX * 4  = 1622016
#define OVF_OFF    165462272u      // 65536 * 8      = 524288
#define WS_NEED    165986560u

__device__ inline void inv3(const double a[9], double inv[9]) {
    double c00 =  a[4]*a[8] - a[5]*a[7];
    double c01 = -(a[3]*a[8] - a[5]*a[6]);
    double c02 =  a[3]*a[7] - a[4]*a[6];
    double det = a[0]*c00 + a[1]*c01 + a[2]*c02;
    double id  = 1.0/det;
    inv[0] = c00*id;
    inv[1] = (a[2]*a[7]-a[1]*a[8])*id;
    inv[2] = (a[1]*a[5]-a[2]*a[4])*id;
    inv[3] = c01*id;
    inv[4] = (a[0]*a[8]-a[2]*a[6])*id;
    inv[5] = (a[2]*a[3]-a[0]*a[5])*id;
    inv[6] = c02*id;
    inv[7] = (a[1]*a[6]-a[0]*a[7])*id;
    inv[8] = (a[0]*a[4]-a[1]*a[3])*id;
}

// o[0..8]=inv(post_rots), [9..17]=rots@inv(intrins), [18..20]=post_trans, [21..23]=trans
__device__ inline void prep_bn(const float* __restrict__ rots,
                               const float* __restrict__ trans,
                               const float* __restrict__ intrins,
                               const float* __restrict__ post_rots,
                               const float* __restrict__ post_trans,
                               int bn, double* o) {
    double pr[9], kk[9], rt[9], ipr[9], ik[9];
    #pragma unroll
    for (int i = 0; i < 9; i++) {
        pr[i] = (double)post_rots[bn*9 + i];
        kk[i] = (double)intrins[bn*9 + i];
        rt[i] = (double)rots[bn*9 + i];
    }
    inv3(pr, ipr);
    inv3(kk, ik);
    #pragma unroll
    for (int i = 0; i < 9; i++) o[i] = ipr[i];
    #pragma unroll
    for (int r = 0; r < 3; r++)
        #pragma unroll
        for (int c = 0; c < 3; c++)
            o[9 + r*3 + c] = rt[r*3+0]*ik[0*3+c] + rt[r*3+1]*ik[1*3+c] + rt[r*3+2]*ik[2*3+c];
    #pragma unroll
    for (int i = 0; i < 3; i++) o[18 + i] = (double)post_trans[bn*3 + i];
    #pragma unroll
    for (int i = 0; i < 3; i++) o[21 + i] = (double)trans[bn*3 + i];
}

__global__ void prep_kernel(const float* __restrict__ rots,
                            const float* __restrict__ trans,
                            const float* __restrict__ intrins,
                            const float* __restrict__ post_rots,
                            const float* __restrict__ post_trans,
                            double* __restrict__ tw) {
    int bn = threadIdx.x;
    if (bn >= 12) return;
    prep_bn(rots, trans, intrins, post_rots, post_trans, bn, tw + bn*24);
}

__global__ __launch_bounds__(256) void zero_kernel(float4* __restrict__ p, int n4) {
    int i = blockIdx.x * 256 + threadIdx.x;
    int stride = gridDim.x * 256;
    for (; i < n4; i += stride) p[i] = make_float4(0.f, 0.f, 0.f, 0.f);
}

// zero vcnt (131072 ints as 32768 int4; 128 blk x 256 = exactly one each) + ctrs
__global__ __launch_bounds__(256) void init_cnt(int4* __restrict__ vcnt4, int* __restrict__ ctr) {
    int i = blockIdx.x * 256 + threadIdx.x;
    vcnt4[i] = make_int4(0, 0, 0, 0);
    if (i == 0) { ctr[0] = 0; ctr[1] = 0; }
}

// K1: one thread per column (99 blk x 256 = 25344). Transforms in LDS,
// run-length grouping over static vox[16], wave-aggregated entry alloc,
// slot registration (no linked list). meta = slice<<22 | w<<16 | mask16.
__global__ __launch_bounds__(256) void geom_cols(const float* __restrict__ rots,
                                                 const float* __restrict__ trans,
                                                 const float* __restrict__ intrins,
                                                 const float* __restrict__ post_rots,
                                                 const float* __restrict__ post_trans,
                                                 int* __restrict__ slots,
                                                 int* __restrict__ vcnt,
                                                 int* __restrict__ ctr,
                                                 unsigned* __restrict__ ent_meta,
                                                 int2* __restrict__ ovf) {
    __shared__ double s_t[12 * 24];

    const int tid  = threadIdx.x;
    const int col  = blockIdx.x * 256 + tid;
    const int lane = tid & 63;

    if (tid < 12)
        prep_bn(rots, trans, intrins, post_rots, post_trans, tid, s_t + tid * 24);
    __syncthreads();

    const int slice = col / 44;                   // bn*48 + d
    const int w     = col - slice * 44;
    const int bn    = slice / 48;
    const int d     = slice - bn * 48;
    const int b     = bn / 6;
    const double* t = s_t + bn * 24;

    // per-h voxel ids (statically indexed -> registers)
    int vox[16];
    {
        const float dsv = __fadd_rn(2.0f, __fmul_rn((float)(56.0 / 48.0), (float)d));
        const float xsv = (w == 43) ? 703.0f : (float)((double)w * (703.0 / 43.0));
        const double px = (double)xsv - t[18];
        #pragma unroll
        for (int h = 0; h < 16; h++) {
            float ysv = (float)(h * 17);
            double py = (double)ysv - t[19];
            double pz = (double)dsv - t[20];
            double q0 = t[0]*px + t[1]*py + t[2]*pz;
            double q1 = t[3]*px + t[4]*py + t[5]*pz;
            double q2 = t[6]*px + t[7]*py + t[8]*pz;
            q0 *= q2;
            q1 *= q2;
            double e0 = t[9]*q0  + t[10]*q1 + t[11]*q2 + t[21];
            double e1 = t[12]*q0 + t[13]*q1 + t[14]*q2 + t[22];
            double e2 = t[15]*q0 + t[16]*q1 + t[17]*q2 + t[23];
            const double lxy = (double)(-51.2f);
            const double dxy = (double)(0.4f);
            int gx = (int)((e0 - lxy) / dxy);
            int gy = (int)((e1 - lxy) / dxy);
            int gz = (int)((e2 - (double)(-10.0f)) / (double)(20.0f));
            vox[h] = (gx >= 0 && gx < 256 && gy >= 0 && gy < 256 && gz == 0)
                   ? ((b << 16) | (gy << 8) | gx) : -1;
        }
    }

    // count run-length groups (break at -1 or id change)
    int cnt = 0;
    #pragma unroll
    for (int h = 0; h < 16; h++) {
        int prev = (h == 0) ? -1 : vox[h - 1];
        if (vox[h] >= 0 && vox[h] != prev) cnt++;
    }

    // wave-aggregated allocation (1 atomic per wave)
    int pre = cnt;
    #pragma unroll
    for (int off = 1; off < 64; off <<= 1) {
        int n = __shfl_up(pre, off);
        if (lane >= off) pre += n;
    }
    int wtot  = __shfl(pre, 63);
    int wbase = 0;
    if (wtot > 0) {
        if (lane == 63) wbase = atomicAdd(&ctr[0], wtot);
        wbase = __shfl(wbase, 63);
    }
    int e = wbase + pre - cnt;    // my first entry index

    // emit runs as 16-bit masks; register in slot arrays
    int cur = -1; unsigned mask = 0;
    #pragma unroll
    for (int h = 0; h < 16; h++) {
        if (vox[h] < 0) {
            if (cur >= 0) {
                ent_meta[e] = ((unsigned)slice << 22) | ((unsigned)w << 16) | mask;
                int idx = atomicAdd(&vcnt[cur], 1);
                if (idx < SLOT_STRIDE) slots[(size_t)cur * SLOT_STRIDE + idx] = e;
                else { int o = atomicAdd(&ctr[1], 1); if (o < 65536) ovf[o] = make_int2(cur, e); }
                e++; cur = -1; mask = 0;
            }
        } else if (vox[h] != cur) {
            if (cur >= 0) {
                ent_meta[e] = ((unsigned)slice << 22) | ((unsigned)w << 16) | mask;
                int idx = atomicAdd(&vcnt[cur], 1);
                if (idx < SLOT_STRIDE) slots[(size_t)cur * SLOT_STRIDE + idx] = e;
                else { int o = atomicAdd(&ctr[1], 1); if (o < 65536) ovf[o] = make_int2(cur, e); }
                e++;
            }
            cur = vox[h]; mask = (1u << h);
        } else {
            mask |= (1u << h);
        }
    }
    if (cur >= 0) {
        ent_meta[e] = ((unsigned)slice << 22) | ((unsigned)w << 16) | mask;
        int idx = atomicAdd(&vcnt[cur], 1);
        if (idx < SLOT_STRIDE) slots[(size_t)cur * SLOT_STRIDE + idx] = e;
        else { int o = atomicAdd(&ctr[1], 1); if (o < 65536) ovf[o] = make_int2(cur, e); }
    }
}

// K2: balanced streaming reduce x -> P. One item = (entry, c4); uniform
// UNCONDITIONAL 16x float4 loads (always in-bounds), fmaf-masked -- full
// MLP, no divergence (the R10/R11-proven form).
__global__ __launch_bounds__(256) void reduce_kernel(const float* __restrict__ x,
                                                     const unsigned* __restrict__ ent_meta,
                                                     const int* __restrict__ ctr,
                                                     float* __restrict__ P) {
    const int NE = ctr[0];
    const int total = NE * 20;
    int i = blockIdx.x * 256 + threadIdx.x;
    const int stride = gridDim.x * 256;
    for (; i < total; i += stride) {
        int e  = i / 20;
        int c4 = i - e * 20;
        unsigned meta = ent_meta[e];
        int slice   = (int)(meta >> 22);
        int w       = (int)((meta >> 16) & 63u);
        unsigned mm = meta & 0xFFFFu;
        const float* xb = x + (size_t)(slice * 704 + w) * NCH + c4 * 4;
        float ax = 0.f, ay = 0.f, az = 0.f, aw = 0.f;
        #pragma unroll
        for (int h = 0; h < 16; h++) {
            float4 v = *(const float4*)(xb + h * HSTRIDE);
            float m = (float)((mm >> h) & 1u);
            ax = fmaf(m, v.x, ax);
            ay = fmaf(m, v.y, ay);
            az = fmaf(m, v.z, az);
            aw = fmaf(m, v.w, aw);
        }
        float4 r; r.x = ax; r.y = ay; r.z = az; r.w = aw;
        *(float4*)(P + (size_t)e * NCH + c4 * 4) = r;   // 320B contiguous
    }
}

// K3: per 64-voxel tile: read slot IDs directly (no pointer chase),
// one float4 P-load per (entry,c4), LDS transpose, float4 out writes.
__global__ __launch_bounds__(256, 6) void gather_slots(const float* __restrict__ P,
                                                       const int* __restrict__ slots,
                                                       const int* __restrict__ vcnt,
                                                       const int* __restrict__ ctr,
                                                       const int2* __restrict__ ovf,
                                                       float* __restrict__ out) {
    __shared__ float tile[64 * 81];
    __shared__ int   s_cnt[64];
    __shared__ int   s_novf;

    const int tid = threadIdx.x;
    const int b   = blockIdx.x >> 10;
    const int v0  = (blockIdx.x & 1023) * 64;

    if (tid < 64) s_cnt[tid] = vcnt[(b << 16) + v0 + tid];
    if (tid == 0) s_novf = ctr[1];
    __syncthreads();

    // 64 vox * 20 c4-items = 1280 items, 5 passes
    #pragma unroll
    for (int i = 0; i < 5; i++) {
        int j  = i * 256 + tid;
        int v  = j / 20;
        int c4 = j - v * 20;
        const int vox = (b << 16) + v0 + v;
        const int cnt = s_cnt[v];
        const int cl  = (cnt < SLOT_STRIDE) ? cnt : SLOT_STRIDE;
        const int* sl = slots + (size_t)vox * SLOT_STRIDE;
        float ax = 0.f, ay = 0.f, az = 0.f, aw = 0.f;
        for (int k = 0; k < cl; k++) {
            int e = sl[k];                     // broadcast across 20 c4 lanes
            const float4 p = *(const float4*)(P + (size_t)e * NCH + c4 * 4);
            ax += p.x; ay += p.y; az += p.z; aw += p.w;
        }
        if (cnt > SLOT_STRIDE) {               // correctness net (expected never)
            int no = s_novf; if (no > 65536) no = 65536;
            for (int j2 = 0; j2 < no; j2++) {
                int2 pr = ovf[j2];
                if (pr.x == vox) {
                    const float4 p = *(const float4*)(P + (size_t)pr.y * NCH + c4 * 4);
                    ax += p.x; ay += p.y; az += p.z; aw += p.w;
                }
            }
        }
        tile[v * 81 + c4 * 4 + 0] = ax;
        tile[v * 81 + c4 * 4 + 1] = ay;
        tile[v * 81 + c4 * 4 + 2] = az;
        tile[v * 81 + c4 * 4 + 3] = aw;
    }
    __syncthreads();

    // float4 out writes: 1280 float4 / 256 threads = 5 iters
    #pragma unroll
    for (int i = 0; i < 5; i++) {
        int f   = i * 256 + tid;
        int c   = f >> 4;                 // 0..79
        int lv4 = f & 15;                 // 0..15 (16 float4 per c-row)
        float4 r;
        r.x = tile[(lv4 * 4 + 0) * 81 + c];
        r.y = tile[(lv4 * 4 + 1) * 81 + c];
        r.z = tile[(lv4 * 4 + 2) * 81 + c];
        r.w = tile[(lv4 * 4 + 3) * 81 + c];
        *(float4*)(out + (size_t)b * OUT_PER_B + (size_t)c * GRID_HW + v0 + lv4 * 4) = r;
    }
}

// ---- fallback path (ws too small): R3 structure ----
__device__ inline void geom_points(const double* __restrict__ t,
                                   int b, int d, int tid, int* s_base) {
    const float dsv = __fadd_rn(2.0f, __fmul_rn((float)(56.0 / 48.0), (float)d));
    for (int idx = tid; idx < 704; idx += 256) {
        const int h = idx / 44;
        const int w = idx - h * 44;
        float xsv = (w == 43) ? 703.0f : (float)((double)w * (703.0 / 43.0));
        float ysv = (float)(h * 17);
        double px = (double)xsv - t[18];
        double py = (double)ysv - t[19];
        double pz = (double)dsv - t[20];
        double q0 = t[0]*px + t[1]*py + t[2]*pz;
        double q1 = t[3]*px + t[4]*py + t[5]*pz;
        double q2 = t[6]*px + t[7]*py + t[8]*pz;
        q0 *= q2;
        q1 *= q2;
        double e0 = t[9]*q0  + t[10]*q1 + t[11]*q2 + t[21];
        double e1 = t[12]*q0 + t[13]*q1 + t[14]*q2 + t[22];
        double e2 = t[15]*q0 + t[16]*q1 + t[17]*q2 + t[23];
        const double lxy = (double)(-51.2f);
        const double dxy = (double)(0.4f);
        int gx = (int)((e0 - lxy) / dxy);
        int gy = (int)((e1 - lxy) / dxy);
        int gz = (int)((e2 - (double)(-10.0f)) / (double)(20.0f));
        int base = -1;
        if (gx >= 0 && gx < 256 && gy >= 0 && gy < 256 && gz == 0)
            base = (b << 16) | (gy << 8) | gx;
        s_base[idx] = base;
    }
}

__global__ __launch_bounds__(256) void scatter_direct_kernel(const float* __restrict__ x,
                                                             const double* __restrict__ ws,
                                                             float* __restrict__ out) {
    __shared__ int      s_base[704];
    __shared__ int      s_colbase[44];
    __shared__ unsigned s_mask[44];
    __shared__ unsigned s_fb[44];

    const int tid = threadIdx.x;
    const int bn  = blockIdx.x / 48;
    const int d   = blockIdx.x - bn * 48;
    const int b   = bn / 6;
    geom_points(ws + bn * 24, b, d, tid, s_base);
    __syncthreads();

    if (tid < 44) {
        int cb = -1; unsigned mm = 0, fb = 0;
        #pragma unroll
        for (int h = 0; h < 16; h++) {
            int pb = s_base[h * 44 + tid];
            if (pb >= 0) {
                if (cb < 0) cb = pb;
                if (pb == cb) mm |= (1u << h);
                else          fb |= (1u << h);
            }
        }
        s_colbase[tid] = cb;
        s_mask[tid]    = mm;
        s_fb[tid]      = fb;
    }
    __syncthreads();

    const float* xb0 = x + ((size_t)bn * PTS_PER_BN + (size_t)d * 704) * NCH;
    #pragma unroll
    for (int pass = 0; pass < 4; pass++) {
        int item = pass * 256 + tid;
        if (item >= 880) break;
        int w  = item / 20;
        int c4 = item - w * 20;
        unsigned mm = s_mask[w];
        unsigned fb = s_fb[w];
        if (!(mm | fb)) continue;
        const float* xb = xb0 + (size_t)w * NCH + c4 * 4;
        float ax = 0.f, ay = 0.f, az = 0.f, aw = 0.f;
        #pragma unroll
        for (int h = 0; h < 16; h++) {
            if ((mm >> h) & 1u) {
                float4 v = *(const float4*)(xb + h * HSTRIDE);
                ax += v.x; ay += v.y; az += v.z; aw += v.w;
            } else if ((fb >> h) & 1u) {
                float4 v = *(const float4*)(xb + h * HSTRIDE);
                int vb = s_base[h * 44 + w];
                float* o = out + (size_t)(vb >> 16) * OUT_PER_B + (vb & 65535);
                atomicAdd(o + (size_t)(c4*4 + 0) * GRID_HW, v.x);
                atomicAdd(o + (size_t)(c4*4 + 1) * GRID_HW, v.y);
                atomicAdd(o + (size_t)(c4*4 + 2) * GRID_HW, v.z);
                atomicAdd(o + (size_t)(c4*4 + 3) * GRID_HW, v.w);
            }
        }
        if (mm) {
            int vb = s_colbase[w];
            float* o = out + (size_t)(vb >> 16) * OUT_PER_B + (vb & 65535);
            atomicAdd(o + (size_t)(c4*4 + 0) * GRID_HW, ax);
            atomicAdd(o + (size_t)(c4*4 + 1) * GRID_HW, ay);
            atomicAdd(o + (size_t)(c4*4 + 2) * GRID_HW, az);
            atomicAdd(o + (size_t)(c4*4 + 3) * GRID_HW, aw);
        }
    }
}

extern "C" void kernel_launch(void* const* d_in, const int* in_sizes, int n_in,
                              void* d_out, int out_size, void* d_ws, size_t ws_size,
                              hipStream_t stream) {
    const float* x          = (const float*)d_in[0];
    const float* rots       = (const float*)d_in[1];
    const float* trans      = (const float*)d_in[2];
    const float* intrins    = (const float*)d_in[3];
    const float* post_rots  = (const float*)d_in[4];
    const float* post_trans = (const float*)d_in[5];
    float* out = (float*)d_out;

    if (ws_size >= (size_t)WS_NEED) {
        float*    P     = (float*)d_ws;
        int*      slots = (int*)((char*)d_ws + SLOTS_OFF);
        int*      vcnt  = (int*)((char*)d_ws + VCNT_OFF);
        int*      ctr   = (int*)((char*)d_ws + CTR_OFF);
        unsigned* meta  = (unsigned*)((char*)d_ws + META_OFF);
        int2*     ovf   = (int2*)((char*)d_ws + OVF_OFF);
        init_cnt<<<128, 256, 0, stream>>>((int4*)vcnt, ctr);
        geom_cols<<<99, 256, 0, stream>>>(rots, trans, intrins,
                                          post_rots, post_trans,
                                          slots, vcnt, ctr, meta, ovf);
        reduce_kernel<<<1024, 256, 0, stream>>>(x, meta, ctr, P);
        gather_slots<<<2048, 256, 0, stream>>>(P, slots, vcnt, ctr, ovf, out);
    } else if (ws_size >= 12 * 24 * sizeof(double)) {
        double* tw = (double*)d_ws;
        zero_kernel<<<2560, 256, 0, stream>>>((float4*)out, out_size / 16);
        prep_kernel<<<1, 64, 0, stream>>>(rots, trans, intrins, post_rots, post_trans, tw);
        scatter_direct_kernel<<<576, 256, 0, stream>>>(x, tw, out);
    }
}

// Round 9
// 234.573 us; speedup vs baseline: 1.0118x; 1.0098x over previous
//
#include <hip/hip_runtime.h>

// LSS voxel pooling: B=2,N=6,D=48,FH=16,FW=44,C=80 -> out [2,80,1,256,256]
//
// R14: R13≈R12 (237) proved reduce encoding is neutral => the +12us vs R11
// (224.8) is the slot structure. Refined suspect: R12/R13 gather reads
// sl[k] from sparse 33MB global INSIDE the inner loop; each P-load is
// address-dependent on it (2-level dependent global chain per entry,
// L2-cold). R11 iterated IDs from LDS. Fix (gather-only change vs R13):
// block-cooperatively stage up to 32 slot IDs/voxel into LDS via
// COALESCED reads (lanes 0-31 <- slots[vox*64+0..31], 128B contiguous,
// no chase), inner loop indexes LDS. Overflow 32-64 -> global (rare),
// >64 -> ovf net. Predicted total ~223-228; if still ~237 => geom slot
// registration is the cost, revert to R11.
//
// Numerics: f64 geometry seeded with bit-exact f32 frustum values +
// f32-valued bounds constants; trunc-toward-zero. Per-entry f32 h-sum in
// reference (h-ascending) order; f32 across entries (validated R6-R13).

#define NCH       80
#define GRID_HW   65536    // 256*256
#define OUT_PER_B 5242880  // 80*65536
#define HSTRIDE   3520     // 44*80 floats between h rows
#define PTS_PER_BN 33792   // 48*16*44
#define NCOLS     25344    // 576 slices * 44 cols
#define SLOT_STRIDE 64
#define LCAP      32       // LDS-staged IDs per voxel

// workspace layout (bytes)
#define N_ENT_MAX 405504           // 25344 cols x 16 groups worst case
#define P_BYTES    129761280u      // N_ENT_MAX * 80 * 4
#define SLOTS_OFF  129761280u      // 131072 * 64 * 4 = 33554432
#define VCNT_OFF   163315712u      // 131072 * 4     = 524288
#define CTR_OFF    163840000u      // 256  ([0]=entry ctr, [1]=ovf ctr)
#define META_OFF   163840256u      // N_ENT_MAX * 4  = 1622016
#define OVF_OFF    165462272u      // 65536 * 8      = 524288
#define WS_NEED    165986560u

__device__ inline void inv3(const double a[9], double inv[9]) {
    double c00 =  a[4]*a[8] - a[5]*a[7];
    double c01 = -(a[3]*a[8] - a[5]*a[6]);
    double c02 =  a[3]*a[7] - a[4]*a[6];
    double det = a[0]*c00 + a[1]*c01 + a[2]*c02;
    double id  = 1.0/det;
    inv[0] = c00*id;
    inv[1] = (a[2]*a[7]-a[1]*a[8])*id;
    inv[2] = (a[1]*a[5]-a[2]*a[4])*id;
    inv[3] = c01*id;
    inv[4] = (a[0]*a[8]-a[2]*a[6])*id;
    inv[5] = (a[2]*a[3]-a[0]*a[5])*id;
    inv[6] = c02*id;
    inv[7] = (a[1]*a[6]-a[0]*a[7])*id;
    inv[8] = (a[0]*a[4]-a[1]*a[3])*id;
}

// o[0..8]=inv(post_rots), [9..17]=rots@inv(intrins), [18..20]=post_trans, [21..23]=trans
__device__ inline void prep_bn(const float* __restrict__ rots,
                               const float* __restrict__ trans,
                               const float* __restrict__ intrins,
                               const float* __restrict__ post_rots,
                               const float* __restrict__ post_trans,
                               int bn, double* o) {
    double pr[9], kk[9], rt[9], ipr[9], ik[9];
    #pragma unroll
    for (int i = 0; i < 9; i++) {
        pr[i] = (double)post_rots[bn*9 + i];
        kk[i] = (double)intrins[bn*9 + i];
        rt[i] = (double)rots[bn*9 + i];
    }
    inv3(pr, ipr);
    inv3(kk, ik);
    #pragma unroll
    for (int i = 0; i < 9; i++) o[i] = ipr[i];
    #pragma unroll
    for (int r = 0; r < 3; r++)
        #pragma unroll
        for (int c = 0; c < 3; c++)
            o[9 + r*3 + c] = rt[r*3+0]*ik[0*3+c] + rt[r*3+1]*ik[1*3+c] + rt[r*3+2]*ik[2*3+c];
    #pragma unroll
    for (int i = 0; i < 3; i++) o[18 + i] = (double)post_trans[bn*3 + i];
    #pragma unroll
    for (int i = 0; i < 3; i++) o[21 + i] = (double)trans[bn*3 + i];
}

__global__ void prep_kernel(const float* __restrict__ rots,
                            const float* __restrict__ trans,
                            const float* __restrict__ intrins,
                            const float* __restrict__ post_rots,
                            const float* __restrict__ post_trans,
                            double* __restrict__ tw) {
    int bn = threadIdx.x;
    if (bn >= 12) return;
    prep_bn(rots, trans, intrins, post_rots, post_trans, bn, tw + bn*24);
}

__global__ __launch_bounds__(256) void zero_kernel(float4* __restrict__ p, int n4) {
    int i = blockIdx.x * 256 + threadIdx.x;
    int stride = gridDim.x * 256;
    for (; i < n4; i += stride) p[i] = make_float4(0.f, 0.f, 0.f, 0.f);
}

// zero vcnt (131072 ints as 32768 int4; 128 blk x 256 = exactly one each) + ctrs
__global__ __launch_bounds__(256) void init_cnt(int4* __restrict__ vcnt4, int* __restrict__ ctr) {
    int i = blockIdx.x * 256 + threadIdx.x;
    vcnt4[i] = make_int4(0, 0, 0, 0);
    if (i == 0) { ctr[0] = 0; ctr[1] = 0; }
}

// K1: one thread per column (99 blk x 256 = 25344). Transforms in LDS,
// run-length grouping over static vox[16], wave-aggregated entry alloc,
// slot registration (no linked list). meta = slice<<22 | w<<16 | mask16.
__global__ __launch_bounds__(256) void geom_cols(const float* __restrict__ rots,
                                                 const float* __restrict__ trans,
                                                 const float* __restrict__ intrins,
                                                 const float* __restrict__ post_rots,
                                                 const float* __restrict__ post_trans,
                                                 int* __restrict__ slots,
                                                 int* __restrict__ vcnt,
                                                 int* __restrict__ ctr,
                                                 unsigned* __restrict__ ent_meta,
                                                 int2* __restrict__ ovf) {
    __shared__ double s_t[12 * 24];

    const int tid  = threadIdx.x;
    const int col  = blockIdx.x * 256 + tid;
    const int lane = tid & 63;

    if (tid < 12)
        prep_bn(rots, trans, intrins, post_rots, post_trans, tid, s_t + tid * 24);
    __syncthreads();

    const int slice = col / 44;                   // bn*48 + d
    const int w     = col - slice * 44;
    const int bn    = slice / 48;
    const int d     = slice - bn * 48;
    const int b     = bn / 6;
    const double* t = s_t + bn * 24;

    // per-h voxel ids (statically indexed -> registers)
    int vox[16];
    {
        const float dsv = __fadd_rn(2.0f, __fmul_rn((float)(56.0 / 48.0), (float)d));
        const float xsv = (w == 43) ? 703.0f : (float)((double)w * (703.0 / 43.0));
        const double px = (double)xsv - t[18];
        #pragma unroll
        for (int h = 0; h < 16; h++) {
            float ysv = (float)(h * 17);
            double py = (double)ysv - t[19];
            double pz = (double)dsv - t[20];
            double q0 = t[0]*px + t[1]*py + t[2]*pz;
            double q1 = t[3]*px + t[4]*py + t[5]*pz;
            double q2 = t[6]*px + t[7]*py + t[8]*pz;
            q0 *= q2;
            q1 *= q2;
            double e0 = t[9]*q0  + t[10]*q1 + t[11]*q2 + t[21];
            double e1 = t[12]*q0 + t[13]*q1 + t[14]*q2 + t[22];
            double e2 = t[15]*q0 + t[16]*q1 + t[17]*q2 + t[23];
            const double lxy = (double)(-51.2f);
            const double dxy = (double)(0.4f);
            int gx = (int)((e0 - lxy) / dxy);
            int gy = (int)((e1 - lxy) / dxy);
            int gz = (int)((e2 - (double)(-10.0f)) / (double)(20.0f));
            vox[h] = (gx >= 0 && gx < 256 && gy >= 0 && gy < 256 && gz == 0)
                   ? ((b << 16) | (gy << 8) | gx) : -1;
        }
    }

    // count run-length groups (break at -1 or id change)
    int cnt = 0;
    #pragma unroll
    for (int h = 0; h < 16; h++) {
        int prev = (h == 0) ? -1 : vox[h - 1];
        if (vox[h] >= 0 && vox[h] != prev) cnt++;
    }

    // wave-aggregated allocation (1 atomic per wave)
    int pre = cnt;
    #pragma unroll
    for (int off = 1; off < 64; off <<= 1) {
        int n = __shfl_up(pre, off);
        if (lane >= off) pre += n;
    }
    int wtot  = __shfl(pre, 63);
    int wbase = 0;
    if (wtot > 0) {
        if (lane == 63) wbase = atomicAdd(&ctr[0], wtot);
        wbase = __shfl(wbase, 63);
    }
    int e = wbase + pre - cnt;    // my first entry index

    // emit runs as 16-bit masks; register in slot arrays
    int cur = -1; unsigned mask = 0;
    #pragma unroll
    for (int h = 0; h < 16; h++) {
        if (vox[h] < 0) {
            if (cur >= 0) {
                ent_meta[e] = ((unsigned)slice << 22) | ((unsigned)w << 16) | mask;
                int idx = atomicAdd(&vcnt[cur], 1);
                if (idx < SLOT_STRIDE) slots[(size_t)cur * SLOT_STRIDE + idx] = e;
                else { int o = atomicAdd(&ctr[1], 1); if (o < 65536) ovf[o] = make_int2(cur, e); }
                e++; cur = -1; mask = 0;
            }
        } else if (vox[h] != cur) {
            if (cur >= 0) {
                ent_meta[e] = ((unsigned)slice << 22) | ((unsigned)w << 16) | mask;
                int idx = atomicAdd(&vcnt[cur], 1);
                if (idx < SLOT_STRIDE) slots[(size_t)cur * SLOT_STRIDE + idx] = e;
                else { int o = atomicAdd(&ctr[1], 1); if (o < 65536) ovf[o] = make_int2(cur, e); }
                e++;
            }
            cur = vox[h]; mask = (1u << h);
        } else {
            mask |= (1u << h);
        }
    }
    if (cur >= 0) {
        ent_meta[e] = ((unsigned)slice << 22) | ((unsigned)w << 16) | mask;
        int idx = atomicAdd(&vcnt[cur], 1);
        if (idx < SLOT_STRIDE) slots[(size_t)cur * SLOT_STRIDE + idx] = e;
        else { int o = atomicAdd(&ctr[1], 1); if (o < 65536) ovf[o] = make_int2(cur, e); }
    }
}

// K2: balanced streaming reduce x -> P. One item = (entry, c4); uniform
// unconditional 16x float4 loads, fmaf-masked (the R10/R11-proven form).
__global__ __launch_bounds__(256) void reduce_kernel(const float* __restrict__ x,
                                                     const unsigned* __restrict__ ent_meta,
                                                     const int* __restrict__ ctr,
                                                     float* __restrict__ P) {
    const int NE = ctr[0];
    const int total = NE * 20;
    int i = blockIdx.x * 256 + threadIdx.x;
    const int stride = gridDim.x * 256;
    for (; i < total; i += stride) {
        int e  = i / 20;
        int c4 = i - e * 20;
        unsigned meta = ent_meta[e];
        int slice   = (int)(meta >> 22);
        int w       = (int)((meta >> 16) & 63u);
        unsigned mm = meta & 0xFFFFu;
        const float* xb = x + (size_t)(slice * 704 + w) * NCH + c4 * 4;
        float ax = 0.f, ay = 0.f, az = 0.f, aw = 0.f;
        #pragma unroll
        for (int h = 0; h < 16; h++) {
            float4 v = *(const float4*)(xb + h * HSTRIDE);
            float m = (float)((mm >> h) & 1u);
            ax = fmaf(m, v.x, ax);
            ay = fmaf(m, v.y, ay);
            az = fmaf(m, v.z, az);
            aw = fmaf(m, v.w, aw);
        }
        float4 r; r.x = ax; r.y = ay; r.z = az; r.w = aw;
        *(float4*)(P + (size_t)e * NCH + c4 * 4) = r;   // 320B contiguous
    }
}

// K3: per 64-voxel tile: stage up to LCAP slot IDs/voxel into LDS with
// COALESCED loads (no pointer chase, no dependent global chain), inner
// loop indexes LDS; overflow LCAP..64 reads global (rare), >64 ovf net.
__global__ __launch_bounds__(256) void gather_slots(const float* __restrict__ P,
                                                    const int* __restrict__ slots,
                                                    const int* __restrict__ vcnt,
                                                    const int* __restrict__ ctr,
                                                    const int2* __restrict__ ovf,
                                                    float* __restrict__ out) {
    __shared__ float tile[64 * 81];
    __shared__ int   s_ent[64 * LCAP];
    __shared__ int   s_cnt[64];
    __shared__ int   s_novf;

    const int tid = threadIdx.x;
    const int b   = blockIdx.x >> 10;
    const int v0  = (blockIdx.x & 1023) * 64;

    if (tid < 64) s_cnt[tid] = vcnt[(b << 16) + v0 + tid];
    if (tid == 0) s_novf = ctr[1];
    __syncthreads();

    // stage slot IDs: lanes 0..31 read slots[vox*64 + 0..31] (128B contig)
    #pragma unroll
    for (int i = 0; i < (64 * LCAP) / 256; i++) {
        int idx = i * 256 + tid;
        int v   = idx >> 5;               // LCAP = 32
        int k   = idx & (LCAP - 1);
        if (k < s_cnt[v])
            s_ent[idx] = slots[(size_t)((b << 16) + v0 + v) * SLOT_STRIDE + k];
    }
    __syncthreads();

    // 64 vox * 20 c4-items = 1280 items, 5 passes
    #pragma unroll
    for (int i = 0; i < 5; i++) {
        int j  = i * 256 + tid;
        int v  = j / 20;
        int c4 = j - v * 20;
        const int vox = (b << 16) + v0 + v;
        const int cnt = s_cnt[v];
        const int cl  = (cnt < LCAP) ? cnt : LCAP;
        float ax = 0.f, ay = 0.f, az = 0.f, aw = 0.f;
        for (int k = 0; k < cl; k++) {
            int e = s_ent[(v << 5) + k];       // LDS broadcast
            const float4 p = *(const float4*)(P + (size_t)e * NCH + c4 * 4);
            ax += p.x; ay += p.y; az += p.z; aw += p.w;
        }
        if (cnt > LCAP) {                      // rare: 32..64 from global
            const int ch = (cnt < SLOT_STRIDE) ? cnt : SLOT_STRIDE;
            const int* sl = slots + (size_t)vox * SLOT_STRIDE;
            for (int k = LCAP; k < ch; k++) {
                int e = sl[k];
                const float4 p = *(const float4*)(P + (size_t)e * NCH + c4 * 4);
                ax += p.x; ay += p.y; az += p.z; aw += p.w;
            }
        }
        if (cnt > SLOT_STRIDE) {               // correctness net (expected never)
            int no = s_novf; if (no > 65536) no = 65536;
            for (int j2 = 0; j2 < no; j2++) {
                int2 pr = ovf[j2];
                if (pr.x == vox) {
                    const float4 p = *(const float4*)(P + (size_t)pr.y * NCH + c4 * 4);
                    ax += p.x; ay += p.y; az += p.z; aw += p.w;
                }
            }
        }
        tile[v * 81 + c4 * 4 + 0] = ax;
        tile[v * 81 + c4 * 4 + 1] = ay;
        tile[v * 81 + c4 * 4 + 2] = az;
        tile[v * 81 + c4 * 4 + 3] = aw;
    }
    __syncthreads();

    // float4 out writes: 1280 float4 / 256 threads = 5 iters
    #pragma unroll
    for (int i = 0; i < 5; i++) {
        int f   = i * 256 + tid;
        int c   = f >> 4;                 // 0..79
        int lv4 = f & 15;                 // 0..15 (16 float4 per c-row)
        float4 r;
        r.x = tile[(lv4 * 4 + 0) * 81 + c];
        r.y = tile[(lv4 * 4 + 1) * 81 + c];
        r.z = tile[(lv4 * 4 + 2) * 81 + c];
        r.w = tile[(lv4 * 4 + 3) * 81 + c];
        *(float4*)(out + (size_t)b * OUT_PER_B + (size_t)c * GRID_HW + v0 + lv4 * 4) = r;
    }
}

// ---- fallback path (ws too small): R3 structure ----
__device__ inline void geom_points(const double* __restrict__ t,
                                   int b, int d, int tid, int* s_base) {
    const float dsv = __fadd_rn(2.0f, __fmul_rn((float)(56.0 / 48.0), (float)d));
    for (int idx = tid; idx < 704; idx += 256) {
        const int h = idx / 44;
        const int w = idx - h * 44;
        float xsv = (w == 43) ? 703.0f : (float)((double)w * (703.0 / 43.0));
        float ysv = (float)(h * 17);
        double px = (double)xsv - t[18];
        double py = (double)ysv - t[19];
        double pz = (double)dsv - t[20];
        double q0 = t[0]*px + t[1]*py + t[2]*pz;
        double q1 = t[3]*px + t[4]*py + t[5]*pz;
        double q2 = t[6]*px + t[7]*py + t[8]*pz;
        q0 *= q2;
        q1 *= q2;
        double e0 = t[9]*q0  + t[10]*q1 + t[11]*q2 + t[21];
        double e1 = t[12]*q0 + t[13]*q1 + t[14]*q2 + t[22];
        double e2 = t[15]*q0 + t[16]*q1 + t[17]*q2 + t[23];
        const double lxy = (double)(-51.2f);
        const double dxy = (double)(0.4f);
        int gx = (int)((e0 - lxy) / dxy);
        int gy = (int)((e1 - lxy) / dxy);
        int gz = (int)((e2 - (double)(-10.0f)) / (double)(20.0f));
        int base = -1;
        if (gx >= 0 && gx < 256 && gy >= 0 && gy < 256 && gz == 0)
            base = (b << 16) | (gy << 8) | gx;
        s_base[idx] = base;
    }
}

__global__ __launch_bounds__(256) void scatter_direct_kernel(const float* __restrict__ x,
                                                             const double* __restrict__ ws,
                                                             float* __restrict__ out) {
    __shared__ int      s_base[704];
    __shared__ int      s_colbase[44];
    __shared__ unsigned s_mask[44];
    __shared__ unsigned s_fb[44];

    const int tid = threadIdx.x;
    const int bn  = blockIdx.x / 48;
    const int d   = blockIdx.x - bn * 48;
    const int b   = bn / 6;
    geom_points(ws + bn * 24, b, d, tid, s_base);
    __syncthreads();

    if (tid < 44) {
        int cb = -1; unsigned mm = 0, fb = 0;
        #pragma unroll
        for (int h = 0; h < 16; h++) {
            int pb = s_base[h * 44 + tid];
            if (pb >= 0) {
                if (cb < 0) cb = pb;
                if (pb == cb) mm |= (1u << h);
                else          fb |= (1u << h);
            }
        }
        s_colbase[tid] = cb;
        s_mask[tid]    = mm;
        s_fb[tid]      = fb;
    }
    __syncthreads();

    const float* xb0 = x + ((size_t)bn * PTS_PER_BN + (size_t)d * 704) * NCH;
    #pragma unroll
    for (int pass = 0; pass < 4; pass++) {
        int item = pass * 256 + tid;
        if (item >= 880) break;
        int w  = item / 20;
        int c4 = item - w * 20;
        unsigned mm = s_mask[w];
        unsigned fb = s_fb[w];
        if (!(mm | fb)) continue;
        const float* xb = xb0 + (size_t)w * NCH + c4 * 4;
        float ax = 0.f, ay = 0.f, az = 0.f, aw = 0.f;
        #pragma unroll
        for (int h = 0; h < 16; h++) {
            if ((mm >> h) & 1u) {
                float4 v = *(const float4*)(xb + h * HSTRIDE);
                ax += v.x; ay += v.y; az += v.z; aw += v.w;
            } else if ((fb >> h) & 1u) {
                float4 v = *(const float4*)(xb + h * HSTRIDE);
                int vb = s_base[h * 44 + w];
                float* o = out + (size_t)(vb >> 16) * OUT_PER_B + (vb & 65535);
                atomicAdd(o + (size_t)(c4*4 + 0) * GRID_HW, v.x);
                atomicAdd(o + (size_t)(c4*4 + 1) * GRID_HW, v.y);
                atomicAdd(o + (size_t)(c4*4 + 2) * GRID_HW, v.z);
                atomicAdd(o + (size_t)(c4*4 + 3) * GRID_HW, v.w);
            }
        }
        if (mm) {
            int vb = s_colbase[w];
            float* o = out + (size_t)(vb >> 16) * OUT_PER_B + (vb & 65535);
            atomicAdd(o + (size_t)(c4*4 + 0) * GRID_HW, ax);
            atomicAdd(o + (size_t)(c4*4 + 1) * GRID_HW, ay);
            atomicAdd(o + (size_t)(c4*4 + 2) * GRID_HW, az);
            atomicAdd(o + (size_t)(c4*4 + 3) * GRID_HW, aw);
        }
    }
}

extern "C" void kernel_launch(void* const* d_in, const int* in_sizes, int n_in,
                              void* d_out, int out_size, void* d_ws, size_t ws_size,
                              hipStream_t stream) {
    const float* x          = (const float*)d_in[0];
    const float* rots       = (const float*)d_in[1];
    const float* trans      = (const float*)d_in[2];
    const float* intrins    = (const float*)d_in[3];
    const float* post_rots  = (const float*)d_in[4];
    const float* post_trans = (const float*)d_in[5];
    float* out = (float*)d_out;

    if (ws_size >= (size_t)WS_NEED) {
        float*    P     = (float*)d_ws;
        int*      slots = (int*)((char*)d_ws + SLOTS_OFF);
        int*      vcnt  = (int*)((char*)d_ws + VCNT_OFF);
        int*      ctr   = (int*)((char*)d_ws + CTR_OFF);
        unsigned* meta  = (unsigned*)((char*)d_ws + META_OFF);
        int2*     ovf   = (int2*)((char*)d_ws + OVF_OFF);
        init_cnt<<<128, 256, 0, stream>>>((int4*)vcnt, ctr);
        geom_cols<<<99, 256, 0, stream>>>(rots, trans, intrins,
                                          post_rots, post_trans,
                                          slots, vcnt, ctr, meta, ovf);
        reduce_kernel<<<1024, 256, 0, stream>>>(x, meta, ctr, P);
        gather_slots<<<2048, 256, 0, stream>>>(P, slots, vcnt, ctr, ovf, out);
    } else if (ws_size >= 12 * 24 * sizeof(double)) {
        double* tw = (double*)d_ws;
        zero_kernel<<<2560, 256, 0, stream>>>((float4*)out, out_size / 16);
        prep_kernel<<<1, 64, 0, stream>>>(rots, trans, intrins, post_rots, post_trans, tw);
        scatter_direct_kernel<<<576, 256, 0, stream>>>(x, tw, out);
    }
}

// Round 10
// 227.846 us; speedup vs baseline: 1.0417x; 1.0295x over previous
//
#include <hip/hip_runtime.h>

// LSS voxel pooling: B=2,N=6,D=48,FH=16,FW=44,C=80 -> out [2,80,1,256,256]
//
// R15: slot-structure arc (R12-R14) failed: +12.5/+12.1/+9.8us vs R11's
// 224.8 -- producer-side scattered vcnt/slot atomics over 33MB cost more
// than the consumer-side dependent-load fix recovered. REVERT to R11
// wholesale (lists + chain-staged gather, the measured champion). Single
// delta: init_heads kernel -> 2x hipMemsetAsync (0xFF over head = -1 per
// word; 0 over counter). Graph-capture-safe (harness poison fills are
// stream memsets), one fewer dispatch + tail drain.
// Predicted 220-226; >=230 => R11 was fill-variance luck, plateau ~228+-4.
//
// Numerics: f64 geometry seeded with bit-exact f32 frustum values +
// f32-valued bounds constants; trunc-toward-zero. Per-entry f32 h-sum in
// reference (h-ascending) order; f32 across entries (validated R6-R14).

#define NCH       80
#define GRID_HW   65536    // 256*256
#define OUT_PER_B 5242880  // 80*65536
#define HSTRIDE   3520     // 44*80 floats between h rows
#define PTS_PER_BN 33792   // 48*16*44
#define NCOLS     25344    // 576 slices * 44 cols
#define CAP       16       // staged entries per voxel (overflow -> walk)

// workspace layout (bytes)
#define N_ENT_MAX 405504           // 25344 cols x 16 groups worst case
#define P_BYTES   129761280u       // N_ENT_MAX * 80 * 4
#define NEXT_OFF  129761280u       // + N_ENT_MAX*4 = 1622016
#define HEAD_OFF  131383296u       // + 131072*4   = 524288
#define CNT_OFF   131907584u       // + 256
#define META_OFF  131907840u       // + N_ENT_MAX*4 = 1622016
#define WS_NEED   133529856u

__device__ inline void inv3(const double a[9], double inv[9]) {
    double c00 =  a[4]*a[8] - a[5]*a[7];
    double c01 = -(a[3]*a[8] - a[5]*a[6]);
    double c02 =  a[3]*a[7] - a[4]*a[6];
    double det = a[0]*c00 + a[1]*c01 + a[2]*c02;
    double id  = 1.0/det;
    inv[0] = c00*id;
    inv[1] = (a[2]*a[7]-a[1]*a[8])*id;
    inv[2] = (a[1]*a[5]-a[2]*a[4])*id;
    inv[3] = c01*id;
    inv[4] = (a[0]*a[8]-a[2]*a[6])*id;
    inv[5] = (a[2]*a[3]-a[0]*a[5])*id;
    inv[6] = c02*id;
    inv[7] = (a[1]*a[6]-a[0]*a[7])*id;
    inv[8] = (a[0]*a[4]-a[1]*a[3])*id;
}

// o[0..8]=inv(post_rots), [9..17]=rots@inv(intrins), [18..20]=post_trans, [21..23]=trans
__device__ inline void prep_bn(const float* __restrict__ rots,
                               const float* __restrict__ trans,
                               const float* __restrict__ intrins,
                               const float* __restrict__ post_rots,
                               const float* __restrict__ post_trans,
                               int bn, double* o) {
    double pr[9], kk[9], rt[9], ipr[9], ik[9];
    #pragma unroll
    for (int i = 0; i < 9; i++) {
        pr[i] = (double)post_rots[bn*9 + i];
        kk[i] = (double)intrins[bn*9 + i];
        rt[i] = (double)rots[bn*9 + i];
    }
    inv3(pr, ipr);
    inv3(kk, ik);
    #pragma unroll
    for (int i = 0; i < 9; i++) o[i] = ipr[i];
    #pragma unroll
    for (int r = 0; r < 3; r++)
        #pragma unroll
        for (int c = 0; c < 3; c++)
            o[9 + r*3 + c] = rt[r*3+0]*ik[0*3+c] + rt[r*3+1]*ik[1*3+c] + rt[r*3+2]*ik[2*3+c];
    #pragma unroll
    for (int i = 0; i < 3; i++) o[18 + i] = (double)post_trans[bn*3 + i];
    #pragma unroll
    for (int i = 0; i < 3; i++) o[21 + i] = (double)trans[bn*3 + i];
}

__global__ void prep_kernel(const float* __restrict__ rots,
                            const float* __restrict__ trans,
                            const float* __restrict__ intrins,
                            const float* __restrict__ post_rots,
                            const float* __restrict__ post_trans,
                            double* __restrict__ tw) {
    int bn = threadIdx.x;
    if (bn >= 12) return;
    prep_bn(rots, trans, intrins, post_rots, post_trans, bn, tw + bn*24);
}

__global__ __launch_bounds__(256) void zero_kernel(float4* __restrict__ p, int n4) {
    int i = blockIdx.x * 256 + threadIdx.x;
    int stride = gridDim.x * 256;
    for (; i < n4; i += stride) p[i] = make_float4(0.f, 0.f, 0.f, 0.f);
}

// K1: one thread per column (99 blk x 256 = 25344). Transforms in LDS,
// run-length grouping over static vox[16], wave-aggregated entry alloc,
// LIFO list link. meta = slice<<22 | w<<16 | mask16.
__global__ __launch_bounds__(256) void geom_cols(const float* __restrict__ rots,
                                                 const float* __restrict__ trans,
                                                 const float* __restrict__ intrins,
                                                 const float* __restrict__ post_rots,
                                                 const float* __restrict__ post_trans,
                                                 int* __restrict__ nxt,
                                                 int* __restrict__ head,
                                                 int* __restrict__ counter,
                                                 unsigned* __restrict__ ent_meta) {
    __shared__ double s_t[12 * 24];

    const int tid  = threadIdx.x;
    const int col  = blockIdx.x * 256 + tid;      // 99*256 == 25344 exactly
    const int lane = tid & 63;

    if (tid < 12)
        prep_bn(rots, trans, intrins, post_rots, post_trans, tid, s_t + tid * 24);
    __syncthreads();

    const int slice = col / 44;                   // bn*48 + d
    const int w     = col - slice * 44;
    const int bn    = slice / 48;
    const int d     = slice - bn * 48;
    const int b     = bn / 6;
    const double* t = s_t + bn * 24;

    // per-h voxel ids (statically indexed -> registers)
    int vox[16];
    {
        const float dsv = __fadd_rn(2.0f, __fmul_rn((float)(56.0 / 48.0), (float)d));
        const float xsv = (w == 43) ? 703.0f : (float)((double)w * (703.0 / 43.0));
        const double px = (double)xsv - t[18];
        #pragma unroll
        for (int h = 0; h < 16; h++) {
            float ysv = (float)(h * 17);
            double py = (double)ysv - t[19];
            double pz = (double)dsv - t[20];
            double q0 = t[0]*px + t[1]*py + t[2]*pz;
            double q1 = t[3]*px + t[4]*py + t[5]*pz;
            double q2 = t[6]*px + t[7]*py + t[8]*pz;
            q0 *= q2;
            q1 *= q2;
            double e0 = t[9]*q0  + t[10]*q1 + t[11]*q2 + t[21];
            double e1 = t[12]*q0 + t[13]*q1 + t[14]*q2 + t[22];
            double e2 = t[15]*q0 + t[16]*q1 + t[17]*q2 + t[23];
            const double lxy = (double)(-51.2f);
            const double dxy = (double)(0.4f);
            int gx = (int)((e0 - lxy) / dxy);
            int gy = (int)((e1 - lxy) / dxy);
            int gz = (int)((e2 - (double)(-10.0f)) / (double)(20.0f));
            vox[h] = (gx >= 0 && gx < 256 && gy >= 0 && gy < 256 && gz == 0)
                   ? ((b << 16) | (gy << 8) | gx) : -1;
        }
    }

    // count run-length groups (break at -1 or id change)
    int cnt = 0;
    #pragma unroll
    for (int h = 0; h < 16; h++) {
        int prev = (h == 0) ? -1 : vox[h - 1];
        if (vox[h] >= 0 && vox[h] != prev) cnt++;
    }

    // wave-aggregated allocation (1 atomic per wave)
    int pre = cnt;
    #pragma unroll
    for (int off = 1; off < 64; off <<= 1) {
        int n = __shfl_up(pre, off);
        if (lane >= off) pre += n;
    }
    int wtot  = __shfl(pre, 63);
    int wbase = 0;
    if (wtot > 0) {
        if (lane == 63) wbase = atomicAdd(counter, wtot);
        wbase = __shfl(wbase, 63);
    }
    int e = wbase + pre - cnt;    // my first entry index

    // emit run-length groups
    int cur = -1; unsigned mask = 0;
    #pragma unroll
    for (int h = 0; h < 16; h++) {
        if (vox[h] < 0) {
            if (cur >= 0) {
                ent_meta[e] = ((unsigned)slice << 22) | ((unsigned)w << 16) | mask;
                nxt[e] = atomicExch(&head[cur], e);
                e++; cur = -1; mask = 0;
            }
        } else if (vox[h] != cur) {
            if (cur >= 0) {
                ent_meta[e] = ((unsigned)slice << 22) | ((unsigned)w << 16) | mask;
                nxt[e] = atomicExch(&head[cur], e);
                e++;
            }
            cur = vox[h]; mask = (1u << h);
        } else {
            mask |= (1u << h);
        }
    }
    if (cur >= 0) {
        ent_meta[e] = ((unsigned)slice << 22) | ((unsigned)w << 16) | mask;
        nxt[e] = atomicExch(&head[cur], e);
    }
}

// K2: balanced streaming reduce x -> P. One item = (entry, c4); uniform
// unconditional 16x float4 loads (always in-bounds), fmaf-masked.
__global__ __launch_bounds__(256) void reduce_kernel(const float* __restrict__ x,
                                                     const unsigned* __restrict__ ent_meta,
                                                     const int* __restrict__ counter,
                                                     float* __restrict__ P) {
    const int NE = counter[0];
    const int total = NE * 20;
    int i = blockIdx.x * 256 + threadIdx.x;
    const int stride = gridDim.x * 256;
    for (; i < total; i += stride) {
        int e  = i / 20;
        int c4 = i - e * 20;
        unsigned meta = ent_meta[e];
        int slice   = (int)(meta >> 22);
        int w       = (int)((meta >> 16) & 63u);
        unsigned mm = meta & 0xFFFFu;
        const float* xb = x + (size_t)(slice * 704 + w) * NCH + c4 * 4;
        float ax = 0.f, ay = 0.f, az = 0.f, aw = 0.f;
        #pragma unroll
        for (int h = 0; h < 16; h++) {
            float4 v = *(const float4*)(xb + h * HSTRIDE);
            float m = (float)((mm >> h) & 1u);
            ax = fmaf(m, v.x, ax);
            ay = fmaf(m, v.y, ay);
            az = fmaf(m, v.z, az);
            aw = fmaf(m, v.w, aw);
        }
        float4 r; r.x = ax; r.y = ay; r.z = az; r.w = aw;
        *(float4*)(P + (size_t)e * NCH + c4 * 4) = r;   // 320B contiguous
    }
}

// K3: per 64-voxel tile: stage chains to LDS once, one float4 P-load per
// (entry,c4) (P is L2-resident), f32 across entries, LDS transpose,
// dense coalesced out write (writes ALL of out; no zeroing pass).
__global__ __launch_bounds__(256, 6) void gather_tiled(const float* __restrict__ P,
                                                       const int* __restrict__ nxt,
                                                       const int* __restrict__ head,
                                                       float* __restrict__ out) {
    __shared__ float tile[64 * 81];
    __shared__ int   s_ent[64 * CAP];
    __shared__ int   s_cnt[64];
    __shared__ int   s_ovf[64];

    const int tid = threadIdx.x;
    const int b   = blockIdx.x >> 10;
    const int v0  = (blockIdx.x & 1023) * 64;

    // stage chains once (parallel across 64 voxels; chains are short)
    if (tid < 64) {
        int e = head[(b << 16) + v0 + tid];
        int c = 0;
        while (e >= 0 && c < CAP) { s_ent[tid * CAP + c] = e; c++; e = nxt[e]; }
        s_cnt[tid] = c;
        s_ovf[tid] = e;   // -1 unless chain > CAP
    }
    __syncthreads();

    // 64 vox * 20 c4-items = 1280 items, 5 passes
    #pragma unroll
    for (int i = 0; i < 5; i++) {
        int j  = i * 256 + tid;
        int v  = j / 20;
        int c4 = j - v * 20;
        float ax = 0.f, ay = 0.f, az = 0.f, aw = 0.f;
        const int cnt = s_cnt[v];
        for (int k = 0; k < cnt; k++) {
            const float4 p = *(const float4*)(P + (size_t)s_ent[v * CAP + k] * NCH + c4 * 4);
            ax += p.x; ay += p.y; az += p.z; aw += p.w;
        }
        int e = s_ovf[v];
        while (e >= 0) {          // overflow continuation (rare/never)
            const float4 p = *(const float4*)(P + (size_t)e * NCH + c4 * 4);
            ax += p.x; ay += p.y; az += p.z; aw += p.w;
            e = nxt[e];
        }
        tile[v * 81 + c4 * 4 + 0] = ax;
        tile[v * 81 + c4 * 4 + 1] = ay;
        tile[v * 81 + c4 * 4 + 2] = az;
        tile[v * 81 + c4 * 4 + 3] = aw;
    }
    __syncthreads();

    float* dst = out + (size_t)b * OUT_PER_B + v0;
    #pragma unroll
    for (int i = 0; i < 20; i++) {
        int k  = i * 256 + tid;
        int c  = k >> 6;                // 0..79
        int lv = k & 63;
        dst[(size_t)c * GRID_HW + lv] = tile[lv * 81 + c];  // 256B/wave-row
    }
}

// ---- fallback path (ws too small): R3 structure ----
__device__ inline void geom_points(const double* __restrict__ t,
                                   int b, int d, int tid, int* s_base) {
    const float dsv = __fadd_rn(2.0f, __fmul_rn((float)(56.0 / 48.0), (float)d));
    for (int idx = tid; idx < 704; idx += 256) {
        const int h = idx / 44;
        const int w = idx - h * 44;
        float xsv = (w == 43) ? 703.0f : (float)((double)w * (703.0 / 43.0));
        float ysv = (float)(h * 17);
        double px = (double)xsv - t[18];
        double py = (double)ysv - t[19];
        double pz = (double)dsv - t[20];
        double q0 = t[0]*px + t[1]*py + t[2]*pz;
        double q1 = t[3]*px + t[4]*py + t[5]*pz;
        double q2 = t[6]*px + t[7]*py + t[8]*pz;
        q0 *= q2;
        q1 *= q2;
        double e0 = t[9]*q0  + t[10]*q1 + t[11]*q2 + t[21];
        double e1 = t[12]*q0 + t[13]*q1 + t[14]*q2 + t[22];
        double e2 = t[15]*q0 + t[16]*q1 + t[17]*q2 + t[23];
        const double lxy = (double)(-51.2f);
        const double dxy = (double)(0.4f);
        int gx = (int)((e0 - lxy) / dxy);
        int gy = (int)((e1 - lxy) / dxy);
        int gz = (int)((e2 - (double)(-10.0f)) / (double)(20.0f));
        int base = -1;
        if (gx >= 0 && gx < 256 && gy >= 0 && gy < 256 && gz == 0)
            base = (b << 16) | (gy << 8) | gx;
        s_base[idx] = base;
    }
}

__global__ __launch_bounds__(256) void scatter_direct_kernel(const float* __restrict__ x,
                                                             const double* __restrict__ ws,
                                                             float* __restrict__ out) {
    __shared__ int      s_base[704];
    __shared__ int      s_colbase[44];
    __shared__ unsigned s_mask[44];
    __shared__ unsigned s_fb[44];

    const int tid = threadIdx.x;
    const int bn  = blockIdx.x / 48;
    const int d   = blockIdx.x - bn * 48;
    const int b   = bn / 6;
    geom_points(ws + bn * 24, b, d, tid, s_base);
    __syncthreads();

    if (tid < 44) {
        int cb = -1; unsigned mm = 0, fb = 0;
        #pragma unroll
        for (int h = 0; h < 16; h++) {
            int pb = s_base[h * 44 + tid];
            if (pb >= 0) {
                if (cb < 0) cb = pb;
                if (pb == cb) mm |= (1u << h);
                else          fb |= (1u << h);
            }
        }
        s_colbase[tid] = cb;
        s_mask[tid]    = mm;
        s_fb[tid]      = fb;
    }
    __syncthreads();

    const float* xb0 = x + ((size_t)bn * PTS_PER_BN + (size_t)d * 704) * NCH;
    #pragma unroll
    for (int pass = 0; pass < 4; pass++) {
        int item = pass * 256 + tid;
        if (item >= 880) break;
        int w  = item / 20;
        int c4 = item - w * 20;
        unsigned mm = s_mask[w];
        unsigned fb = s_fb[w];
        if (!(mm | fb)) continue;
        const float* xb = xb0 + (size_t)w * NCH + c4 * 4;
        float ax = 0.f, ay = 0.f, az = 0.f, aw = 0.f;
        #pragma unroll
        for (int h = 0; h < 16; h++) {
            if ((mm >> h) & 1u) {
                float4 v = *(const float4*)(xb + h * HSTRIDE);
                ax += v.x; ay += v.y; az += v.z; aw += v.w;
            } else if ((fb >> h) & 1u) {
                float4 v = *(const float4*)(xb + h * HSTRIDE);
                int vb = s_base[h * 44 + w];
                float* o = out + (size_t)(vb >> 16) * OUT_PER_B + (vb & 65535);
                atomicAdd(o + (size_t)(c4*4 + 0) * GRID_HW, v.x);
                atomicAdd(o + (size_t)(c4*4 + 1) * GRID_HW, v.y);
                atomicAdd(o + (size_t)(c4*4 + 2) * GRID_HW, v.z);
                atomicAdd(o + (size_t)(c4*4 + 3) * GRID_HW, v.w);
            }
        }
        if (mm) {
            int vb = s_colbase[w];
            float* o = out + (size_t)(vb >> 16) * OUT_PER_B + (vb & 65535);
            atomicAdd(o + (size_t)(c4*4 + 0) * GRID_HW, ax);
            atomicAdd(o + (size_t)(c4*4 + 1) * GRID_HW, ay);
            atomicAdd(o + (size_t)(c4*4 + 2) * GRID_HW, az);
            atomicAdd(o + (size_t)(c4*4 + 3) * GRID_HW, aw);
        }
    }
}

extern "C" void kernel_launch(void* const* d_in, const int* in_sizes, int n_in,
                              void* d_out, int out_size, void* d_ws, size_t ws_size,
                              hipStream_t stream) {
    const float* x          = (const float*)d_in[0];
    const float* rots       = (const float*)d_in[1];
    const float* trans      = (const float*)d_in[2];
    const float* intrins    = (const float*)d_in[3];
    const float* post_rots  = (const float*)d_in[4];
    const float* post_trans = (const float*)d_in[5];
    float* out = (float*)d_out;

    if (ws_size >= (size_t)WS_NEED) {
        float*    P       = (float*)d_ws;
        int*      nxt     = (int*)((char*)d_ws + NEXT_OFF);
        int*      head    = (int*)((char*)d_ws + HEAD_OFF);
        int*      counter = (int*)((char*)d_ws + CNT_OFF);
        unsigned* meta    = (unsigned*)((char*)d_ws + META_OFF);
        // head[i] = -1 via 0xFF byte fill; counter = 0. Stream memsets are
        // graph-capture-safe (the harness's own poison fills are memsets).
        hipMemsetAsync(head, 0xFF, 131072 * sizeof(int), stream);
        hipMemsetAsync(counter, 0, sizeof(int), stream);
        geom_cols<<<99, 256, 0, stream>>>(rots, trans, intrins,
                                          post_rots, post_trans,
                                          nxt, head, counter, meta);
        reduce_kernel<<<1024, 256, 0, stream>>>(x, meta, counter, P);
        gather_tiled<<<2048, 256, 0, stream>>>(P, nxt, head, out);
    } else if (ws_size >= 12 * 24 * sizeof(double)) {
        double* tw = (double*)d_ws;
        zero_kernel<<<2560, 256, 0, stream>>>((float4*)out, out_size / 16);
        prep_kernel<<<1, 64, 0, stream>>>(rots, trans, intrins, post_rots, post_trans, tw);
        scatter_direct_kernel<<<576, 256, 0, stream>>>(x, tw, out);
    }
}